// Round 7
// baseline (196.211 us; speedup 1.0000x reference)
//
#include <hip/hip_runtime.h>
#include <hip/hip_bf16.h>
#include <stdint.h>

typedef unsigned short u16;
typedef short bf16x8 __attribute__((ext_vector_type(8)));
typedef float f32x4 __attribute__((ext_vector_type(4)));
typedef float f32x16 __attribute__((ext_vector_type(16)));
typedef u16 u16x4 __attribute__((ext_vector_type(4)));
typedef unsigned int uint2v __attribute__((ext_vector_type(2)));

#define DIMX  1024
#define NHEAD 16
#define DH    64
#define INNER 1024
#define BATCH 2
#define SEQ   2048
#define MTOT  (BATCH*SEQ)   /* 4096 */
#define EQKV  (3*INNER)     /* 3072 */

__device__ __forceinline__ u16 f2bf(float f) {
  unsigned int x = __float_as_uint(f);
  unsigned int r = (x + 0x7FFFu + ((x >> 16) & 1u)) >> 16;
  return (u16)r;
}

__device__ __forceinline__ unsigned int cvtpk(float lo, float hi) {
  unsigned int r;
  asm("v_cvt_pk_bf16_f32 %0, %1, %2" : "=v"(r) : "v"(lo), "v"(hi));
  return r;
}

__device__ __forceinline__ void plswap_u(unsigned int& x, unsigned int& y) {
  auto r = __builtin_amdgcn_permlane32_swap(x, y, false, false);
  x = r[0]; y = r[1];
}
__device__ __forceinline__ void plswap_f2(float v, float& a, float& b) {
  unsigned int x = __float_as_uint(v), y = __float_as_uint(v);
  auto r = __builtin_amdgcn_permlane32_swap(x, y, false, false);
  a = __uint_as_float(r[0]); b = __uint_as_float(r[1]);
}

__device__ __forceinline__ void async16(void* lds, const void* g) {
  __builtin_amdgcn_global_load_lds(
      (const __attribute__((address_space(1))) unsigned int*)g,
      (__attribute__((address_space(3))) unsigned int*)lds,
      16, 0, 0);
}

// staging swizzle: 4 16B-units per 32-col row, unit ^= S(r), S(r)=(r^(r>>2))&3
__device__ __forceinline__ int swz4(int r) { return (r ^ (r >> 2)) & 3; }

// ---------------- fp32 -> bf16 convert ----------------
__global__ void cvt_kernel(const float* __restrict__ in, u16* __restrict__ out, int n4) {
  int i = blockIdx.x * blockDim.x + threadIdx.x;
  if (i < n4) {
    float4 v = ((const float4*)in)[i];
    u16x4 o;
    o[0] = f2bf(v.x); o[1] = f2bf(v.y); o[2] = f2bf(v.z); o[3] = f2bf(v.w);
    ((u16x4*)out)[i] = o;
  }
}

// ---------------- QKV projection GEMM (BK=32 dbuf prefetch) ----------------
__global__ __launch_bounds__(256) void gemm_qkv(const u16* __restrict__ X, const u16* __restrict__ W,
                                                u16* __restrict__ Qo, u16* __restrict__ Ko,
                                                u16* __restrict__ Vt) {
  __shared__ short sAll[16384];
  short* sA = sAll;          // [2][128*32]
  short* sB = sAll + 8192;   // [2][128*32]
  const int tid = threadIdx.x;
  const int wv = tid >> 6, l = tid & 63;
  const int lo = l & 15, hi = l >> 4;
  const int wr = wv >> 1, wc = wv & 1;

  int lin = blockIdx.x;
  int wgid = (lin & 7) * 96 + (lin >> 3);
  const int bx = wgid / 32;
  const int by = wgid % 32;
  const int tn = bx * 128, tm = by * 128;

  f32x4 acc[4][4];
#pragma unroll
  for (int i = 0; i < 4; i++)
#pragma unroll
    for (int j = 0; j < 4; j++) acc[i][j] = (f32x4){0.f, 0.f, 0.f, 0.f};

  auto stage = [&](int buf, int kt) {
    int k0 = kt * 32;
    int off = buf * 4096;
#pragma unroll
    for (int c = 0; c < 2; c++) {
      int R0 = wv * 32 + c * 16;
      int r = R0 + (l >> 2);
      int sc = ((l & 3) ^ swz4(r)) * 8;
      async16(&sA[off + R0 * 32], &X[(size_t)(tm + r) * DIMX + k0 + sc]);
      async16(&sB[off + R0 * 32], &W[(size_t)(tn + r) * DIMX + k0 + sc]);
    }
  };

  stage(0, 0);
  __syncthreads();

  for (int kt = 0; kt < DIMX / 32; kt++) {
    const int buf = kt & 1;
    if (kt + 1 < DIMX / 32) stage(buf ^ 1, kt + 1);
    bf16x8 af[4], bf[4];
#pragma unroll
    for (int i = 0; i < 4; i++) {
      int r = wr * 64 + i * 16 + lo;
      af[i] = *(const bf16x8*)&sA[buf * 4096 + r * 32 + ((hi ^ swz4(r)) * 8)];
    }
#pragma unroll
    for (int j = 0; j < 4; j++) {
      int r = wc * 64 + j * 16 + lo;
      bf[j] = *(const bf16x8*)&sB[buf * 4096 + r * 32 + ((hi ^ swz4(r)) * 8)];
    }
#pragma unroll
    for (int i = 0; i < 4; i++)
#pragma unroll
      for (int j = 0; j < 4; j++)
        acc[i][j] = __builtin_amdgcn_mfma_f32_16x16x32_bf16(af[i], bf[j], acc[i][j], 0, 0, 0);
    __syncthreads();
  }

  const int cls = tn >> 10;
  const float scale = 0.125f * 1.44269504088896f;  // dh^-0.5 * log2(e)

  if (cls < 2) {
#pragma unroll
    for (int i = 0; i < 4; i++) {
      int mbase = tm + wr * 64 + i * 16 + hi * 4;
#pragma unroll
      for (int j = 0; j < 4; j++) {
        int e = tn + wc * 64 + j * 16 + lo;
        int e2 = e & 1023, h = e2 >> 6, d = e2 & 63;
#pragma unroll
        for (int r = 0; r < 4; r++) {
          int mm = mbase + r;
          int b = mm >> 11, n = mm & 2047;
          float v = acc[i][j][r];
          if (cls == 0)
            Qo[(((size_t)(b * NHEAD + h)) * SEQ + n) * DH + d] = f2bf(v * scale);
          else
            Ko[(((size_t)(b * NHEAD + h)) * SEQ + n) * DH + d] = f2bf(v);
        }
      }
    }
  } else {
    // V: bounce through LDS for coalesced transposed writes
#pragma unroll
    for (int i = 0; i < 4; i++) {
#pragma unroll
      for (int j = 0; j < 4; j++) {
        int e = wc * 64 + j * 16 + lo;
#pragma unroll
        for (int r = 0; r < 4; r++) {
          int n = wr * 64 + i * 16 + hi * 4 + r;
          sAll[e * 128 + (((n >> 3) ^ (e & 15)) * 8) + (n & 7)] = (short)f2bf(acc[i][j][r]);
        }
      }
    }
    __syncthreads();
    int er = tid >> 1, half = tid & 1;
    int e2 = tn + er - 2048;
    int h = e2 >> 6, d = e2 & 63;
    int b = tm >> 11, nb = tm & 2047;
    u16* dst = &Vt[(((size_t)(b * NHEAD + h)) * DH + d) * SEQ + nb + half * 64];
#pragma unroll
    for (int k = 0; k < 8; k++) {
      int phys = (half * 8 + k) ^ (er & 15);
      bf16x8 v = *(const bf16x8*)&sAll[er * 128 + phys * 8];
      *(bf16x8*)&dst[k * 8] = v;
    }
  }
}

// ---------------- flash attention (direct-from-L2, barrier-free) ----------------
// Q,K: [B*H][N][64] bf16 (Q pre-scaled by dh^-.5*log2e); Vt: [B*H][64][N]; O: [B*N][1024]
// K/V per head = 512 KB -> L2-resident. No LDS staging (Common-mistake #7 / m169):
// MFMA frags are loaded directly from global (16B-aligned per-lane reads; K-tile rows
// and V-tile row-segments L1-cache across the 8 frag reads). No barriers -> waves
// fully independent, compiler free to pipeline loads across tiles.
__global__ __launch_bounds__(256) void attn_kernel(const u16* __restrict__ Q, const u16* __restrict__ Kd,
                                                   const u16* __restrict__ Vt, u16* __restrict__ O) {
  const int tid = threadIdx.x, wv = tid >> 6, l = tid & 63;
  const int l31 = l & 31, hi5 = l >> 5;

  int lin = blockIdx.y * gridDim.x + blockIdx.x;
  int wgid = (lin & 7) * 64 + (lin >> 3);
  int bx = wgid & 15;
  int bh = wgid >> 4;

  const int qw = bx * 128 + wv * 32;
  const u16* Qb = Q + (size_t)bh * SEQ * DH;
  const u16* Kb = Kd + (size_t)bh * SEQ * DH;
  const u16* Vb = Vt + (size_t)bh * DH * SEQ;

  bf16x8 qf[4];
#pragma unroll
  for (int kd = 0; kd < 4; kd++)
    qf[kd] = *(const bf16x8*)&Qb[(size_t)(qw + l31) * DH + kd * 16 + hi5 * 8];

  f32x16 o0, o1;
#pragma unroll
  for (int r = 0; r < 16; r++) { o0[r] = 0.f; o1[r] = 0.f; }
  float mrun = -1e30f, lsum = 0.f;
  const float THR = 11.0f;

  const u16* Krow0 = &Kb[(size_t)l31 * DH + hi5 * 8];          // + kv0*DH + kd*16
  const u16* Krow1 = &Kb[(size_t)(32 + l31) * DH + hi5 * 8];
  const u16* Vrow0 = &Vb[(size_t)l31 * SEQ + hi5 * 8];         // + kv0 + ks*16
  const u16* Vrow1 = &Vb[(size_t)(32 + l31) * SEQ + hi5 * 8];

  for (int t = 0; t < SEQ / 64; t++) {
    const int kv0 = t * 64;

    // ---- issue all frag loads for this tile up front ----
    bf16x8 kf0[4], kf1[4], vf0[4], vf1[4];
#pragma unroll
    for (int kd = 0; kd < 4; kd++) {
      kf0[kd] = *(const bf16x8*)&Krow0[(size_t)kv0 * DH + kd * 16];
      kf1[kd] = *(const bf16x8*)&Krow1[(size_t)kv0 * DH + kd * 16];
    }
#pragma unroll
    for (int ks = 0; ks < 4; ks++) {
      vf0[ks] = *(const bf16x8*)&Vrow0[kv0 + ks * 16];
      vf1[ks] = *(const bf16x8*)&Vrow1[kv0 + ks * 16];
    }

    // ---- S^T = K Q^T ----
    f32x16 s0, s1;
#pragma unroll
    for (int r = 0; r < 16; r++) { s0[r] = 0.f; s1[r] = 0.f; }
#pragma unroll
    for (int kd = 0; kd < 4; kd++) {
      s0 = __builtin_amdgcn_mfma_f32_32x32x16_bf16(kf0[kd], qf[kd], s0, 0, 0, 0);
      s1 = __builtin_amdgcn_mfma_f32_32x32x16_bf16(kf1[kd], qf[kd], s1, 0, 0, 0);
    }

    // ---- in-register online softmax (log2 domain) ----
    float tr[16];
#pragma unroll
    for (int r = 0; r < 16; r++) tr[r] = fmaxf(s0[r], s1[r]);
#pragma unroll
    for (int st = 8; st > 0; st >>= 1)
#pragma unroll
      for (int r = 0; r < st; r++) tr[r] = fmaxf(tr[r], tr[r + st]);
    float mxa, mxb;
    plswap_f2(tr[0], mxa, mxb);
    float mx = fmaxf(mxa, mxb);

    if (!__all(mx <= mrun + THR)) {
      float mnew = fmaxf(mrun, mx);
      float alpha = __builtin_amdgcn_exp2f(mrun - mnew);
      mrun = mnew;
      lsum *= alpha;
      o0 *= alpha;
      o1 *= alpha;
    }

    float sm[16];
#pragma unroll
    for (int r = 0; r < 16; r++) {
      s0[r] = __builtin_amdgcn_exp2f(s0[r] - mrun);
      s1[r] = __builtin_amdgcn_exp2f(s1[r] - mrun);
      sm[r] = s0[r] + s1[r];
    }
#pragma unroll
    for (int st = 8; st > 0; st >>= 1)
#pragma unroll
      for (int r = 0; r < st; r++) sm[r] += sm[r + st];
    lsum += sm[0];

    // ---- P -> PV B-frags via cvt_pk + permlane32_swap ----
    bf16x8 pa[4];
#pragma unroll
    for (int ks = 0; ks < 4; ks++) {
      const int sft = (ks & 1) * 8;
      float e0 = (ks < 2) ? s0[sft + 0] : s1[sft + 0];
      float e1 = (ks < 2) ? s0[sft + 1] : s1[sft + 1];
      float e2 = (ks < 2) ? s0[sft + 2] : s1[sft + 2];
      float e3 = (ks < 2) ? s0[sft + 3] : s1[sft + 3];
      float e4 = (ks < 2) ? s0[sft + 4] : s1[sft + 4];
      float e5 = (ks < 2) ? s0[sft + 5] : s1[sft + 5];
      float e6 = (ks < 2) ? s0[sft + 6] : s1[sft + 6];
      float e7 = (ks < 2) ? s0[sft + 7] : s1[sft + 7];
      unsigned int w0 = cvtpk(e0, e1);
      unsigned int w1 = cvtpk(e2, e3);
      unsigned int w2 = cvtpk(e4, e5);
      unsigned int w3 = cvtpk(e6, e7);
      plswap_u(w0, w2);
      plswap_u(w1, w3);
      union { unsigned int w[4]; bf16x8 v; } u;
      u.w[0] = w0; u.w[1] = w1; u.w[2] = w2; u.w[3] = w3;
      pa[ks] = u.v;
    }

    // ---- O^T += V^T P^T ----
#pragma unroll
    for (int ks = 0; ks < 4; ks++) {
      o0 = __builtin_amdgcn_mfma_f32_32x32x16_bf16(vf0[ks], pa[ks], o0, 0, 0, 0);
      o1 = __builtin_amdgcn_mfma_f32_32x32x16_bf16(vf1[ks], pa[ks], o1, 0, 0, 0);
    }
  }

  float la, lb;
  plswap_f2(lsum, la, lb);
  float inv = 1.0f / (la + lb);

  int b = bh >> 4, h = bh & 15;
  int q = qw + l31;
  size_t orow = ((size_t)(b * SEQ + q)) * INNER + h * 64;
#pragma unroll
  for (int half = 0; half < 2; half++) {
    const f32x16& oo = half ? o1 : o0;
#pragma unroll
    for (int g = 0; g < 4; g++) {
      uint2v pk2;
      pk2[0] = cvtpk(oo[g * 4 + 0] * inv, oo[g * 4 + 1] * inv);
      pk2[1] = cvtpk(oo[g * 4 + 2] * inv, oo[g * 4 + 3] * inv);
      int dv = half * 32 + g * 8 + 4 * hi5;
      *(uint2v*)&O[orow + dv] = pk2;
    }
  }
}

// ---------------- output projection GEMM (BK=32 dbuf prefetch) ----------------
__global__ __launch_bounds__(256) void gemm_out(const u16* __restrict__ A, const u16* __restrict__ W,
                                                const float* __restrict__ bias, float* __restrict__ out) {
  __shared__ short sAll[16384];
  short* sA = sAll;
  short* sB = sAll + 8192;
  const int tid = threadIdx.x;
  const int wv = tid >> 6, l = tid & 63;
  const int lo = l & 15, hi = l >> 4;
  const int wr = wv >> 1, wc = wv & 1;

  int lin = blockIdx.x;
  int wgid = (lin & 7) * 32 + (lin >> 3);
  const int bx = wgid / 32;
  const int by = wgid % 32;
  const int tn = bx * 128, tm = by * 128;

  f32x4 acc[4][4];
#pragma unroll
  for (int i = 0; i < 4; i++)
#pragma unroll
    for (int j = 0; j < 4; j++) acc[i][j] = (f32x4){0.f, 0.f, 0.f, 0.f};

  auto stage = [&](int buf, int kt) {
    int k0 = kt * 32;
    int off = buf * 4096;
#pragma unroll
    for (int c = 0; c < 2; c++) {
      int R0 = wv * 32 + c * 16;
      int r = R0 + (l >> 2);
      int sc = ((l & 3) ^ swz4(r)) * 8;
      async16(&sA[off + R0 * 32], &A[(size_t)(tm + r) * INNER + k0 + sc]);
      async16(&sB[off + R0 * 32], &W[(size_t)(tn + r) * INNER + k0 + sc]);
    }
  };

  stage(0, 0);
  __syncthreads();

  for (int kt = 0; kt < INNER / 32; kt++) {
    const int buf = kt & 1;
    if (kt + 1 < INNER / 32) stage(buf ^ 1, kt + 1);
    bf16x8 af[4], bf[4];
#pragma unroll
    for (int i = 0; i < 4; i++) {
      int r = wr * 64 + i * 16 + lo;
      af[i] = *(const bf16x8*)&sA[buf * 4096 + r * 32 + ((hi ^ swz4(r)) * 8)];
    }
#pragma unroll
    for (int j = 0; j < 4; j++) {
      int r = wc * 64 + j * 16 + lo;
      bf[j] = *(const bf16x8*)&sB[buf * 4096 + r * 32 + ((hi ^ swz4(r)) * 8)];
    }
#pragma unroll
    for (int i = 0; i < 4; i++)
#pragma unroll
      for (int j = 0; j < 4; j++)
        acc[i][j] = __builtin_amdgcn_mfma_f32_16x16x32_bf16(af[i], bf[j], acc[i][j], 0, 0, 0);
    __syncthreads();
  }

#pragma unroll
  for (int i = 0; i < 4; i++) {
    int mbase = tm + wr * 64 + i * 16 + hi * 4;
#pragma unroll
    for (int j = 0; j < 4; j++) {
      int col = tn + wc * 64 + j * 16 + lo;
      float bv = bias[col];
#pragma unroll
      for (int r = 0; r < 4; r++)
        out[(size_t)(mbase + r) * DIMX + col] = acc[i][j][r] + bv;
    }
  }
}

extern "C" void kernel_launch(void* const* d_in, const int* in_sizes, int n_in,
                              void* d_out, int out_size, void* d_ws, size_t ws_size,
                              hipStream_t stream) {
  const float* x     = (const float*)d_in[0];
  const float* w_qkv = (const float*)d_in[1];
  const float* w_out = (const float*)d_in[2];
  const float* b_out = (const float*)d_in[3];

  char* ws = (char*)d_ws;
  u16* xb    = (u16*)(ws);                         // 8 MB
  u16* wqkvb = (u16*)(ws + (size_t)8  * (1<<20));  // 6 MB
  u16* woutb = (u16*)(ws + (size_t)14 * (1<<20));  // 2 MB
  u16* Qd    = (u16*)(ws + (size_t)16 * (1<<20));  // 8 MB
  u16* Kdd   = (u16*)(ws + (size_t)24 * (1<<20));  // 8 MB
  u16* Vtd   = (u16*)(ws + (size_t)32 * (1<<20));  // 8 MB
  u16* Od    = (u16*)(ws + (size_t)40 * (1<<20));  // 8 MB

  cvt_kernel<<<(MTOT * DIMX / 4 + 255) / 256, 256, 0, stream>>>(x, xb, MTOT * DIMX / 4);
  cvt_kernel<<<(EQKV * DIMX / 4 + 255) / 256, 256, 0, stream>>>(w_qkv, wqkvb, EQKV * DIMX / 4);
  cvt_kernel<<<(DIMX * INNER / 4 + 255) / 256, 256, 0, stream>>>(w_out, woutb, DIMX * INNER / 4);

  gemm_qkv<<<768, 256, 0, stream>>>(xb, wqkvb, Qd, Kdd, Vtd);
  attn_kernel<<<dim3(SEQ / 128, BATCH * NHEAD), 256, 0, stream>>>(Qd, Kdd, Vtd, Od);
  gemm_out<<<256, 256, 0, stream>>>(Od, woutb, b_out, (float*)d_out);
}

// Round 8
// 194.965 us; speedup vs baseline: 1.0064x; 1.0064x over previous
//
#include <hip/hip_runtime.h>
#include <hip/hip_bf16.h>
#include <stdint.h>

typedef unsigned short u16;
typedef short bf16x8 __attribute__((ext_vector_type(8)));
typedef float f32x4 __attribute__((ext_vector_type(4)));
typedef float f32x16 __attribute__((ext_vector_type(16)));
typedef u16 u16x4 __attribute__((ext_vector_type(4)));
typedef unsigned int uint2v __attribute__((ext_vector_type(2)));

#define DIMX  1024
#define NHEAD 16
#define DH    64
#define INNER 1024
#define BATCH 2
#define SEQ   2048
#define MTOT  (BATCH*SEQ)   /* 4096 */
#define EQKV  (3*INNER)     /* 3072 */

__device__ __forceinline__ u16 f2bf(float f) {
  unsigned int x = __float_as_uint(f);
  unsigned int r = (x + 0x7FFFu + ((x >> 16) & 1u)) >> 16;
  return (u16)r;
}

__device__ __forceinline__ unsigned int cvtpk(float lo, float hi) {
  unsigned int r;
  asm("v_cvt_pk_bf16_f32 %0, %1, %2" : "=v"(r) : "v"(lo), "v"(hi));
  return r;
}

__device__ __forceinline__ void plswap_u(unsigned int& x, unsigned int& y) {
  auto r = __builtin_amdgcn_permlane32_swap(x, y, false, false);
  x = r[0]; y = r[1];
}
__device__ __forceinline__ void plswap_f2(float v, float& a, float& b) {
  unsigned int x = __float_as_uint(v), y = __float_as_uint(v);
  auto r = __builtin_amdgcn_permlane32_swap(x, y, false, false);
  a = __uint_as_float(r[0]); b = __uint_as_float(r[1]);
}

__device__ __forceinline__ void async16(void* lds, const void* g) {
  __builtin_amdgcn_global_load_lds(
      (const __attribute__((address_space(1))) unsigned int*)g,
      (__attribute__((address_space(3))) unsigned int*)lds,
      16, 0, 0);
}

// staging swizzle: 4 16B-units per 32-col row, unit ^= S(r), S(r)=(r^(r>>2))&3
__device__ __forceinline__ int swz4(int r) { return (r ^ (r >> 2)) & 3; }

// ---------------- fp32 -> bf16 convert ----------------
__global__ void cvt_kernel(const float* __restrict__ in, u16* __restrict__ out, int n4) {
  int i = blockIdx.x * blockDim.x + threadIdx.x;
  if (i < n4) {
    float4 v = ((const float4*)in)[i];
    u16x4 o;
    o[0] = f2bf(v.x); o[1] = f2bf(v.y); o[2] = f2bf(v.z); o[3] = f2bf(v.w);
    ((u16x4*)out)[i] = o;
  }
}

// ---------------- QKV projection GEMM (BK=32 dbuf prefetch) ----------------
__global__ __launch_bounds__(256) void gemm_qkv(const u16* __restrict__ X, const u16* __restrict__ W,
                                                u16* __restrict__ Qo, u16* __restrict__ Ko,
                                                u16* __restrict__ Vt) {
  __shared__ short sAll[16384];
  short* sA = sAll;          // [2][128*32]
  short* sB = sAll + 8192;   // [2][128*32]
  const int tid = threadIdx.x;
  const int wv = tid >> 6, l = tid & 63;
  const int lo = l & 15, hi = l >> 4;
  const int wr = wv >> 1, wc = wv & 1;

  int lin = blockIdx.x;
  int wgid = (lin & 7) * 96 + (lin >> 3);
  const int bx = wgid / 32;
  const int by = wgid % 32;
  const int tn = bx * 128, tm = by * 128;

  f32x4 acc[4][4];
#pragma unroll
  for (int i = 0; i < 4; i++)
#pragma unroll
    for (int j = 0; j < 4; j++) acc[i][j] = (f32x4){0.f, 0.f, 0.f, 0.f};

  auto stage = [&](int buf, int kt) {
    int k0 = kt * 32;
    int off = buf * 4096;
#pragma unroll
    for (int c = 0; c < 2; c++) {
      int R0 = wv * 32 + c * 16;
      int r = R0 + (l >> 2);
      int sc = ((l & 3) ^ swz4(r)) * 8;
      async16(&sA[off + R0 * 32], &X[(size_t)(tm + r) * DIMX + k0 + sc]);
      async16(&sB[off + R0 * 32], &W[(size_t)(tn + r) * DIMX + k0 + sc]);
    }
  };

  stage(0, 0);
  __syncthreads();

  for (int kt = 0; kt < DIMX / 32; kt++) {
    const int buf = kt & 1;
    if (kt + 1 < DIMX / 32) stage(buf ^ 1, kt + 1);
    bf16x8 af[4], bf[4];
#pragma unroll
    for (int i = 0; i < 4; i++) {
      int r = wr * 64 + i * 16 + lo;
      af[i] = *(const bf16x8*)&sA[buf * 4096 + r * 32 + ((hi ^ swz4(r)) * 8)];
    }
#pragma unroll
    for (int j = 0; j < 4; j++) {
      int r = wc * 64 + j * 16 + lo;
      bf[j] = *(const bf16x8*)&sB[buf * 4096 + r * 32 + ((hi ^ swz4(r)) * 8)];
    }
#pragma unroll
    for (int i = 0; i < 4; i++)
#pragma unroll
      for (int j = 0; j < 4; j++)
        acc[i][j] = __builtin_amdgcn_mfma_f32_16x16x32_bf16(af[i], bf[j], acc[i][j], 0, 0, 0);
    __syncthreads();
  }

  const int cls = tn >> 10;
  const float scale = 0.125f * 1.44269504088896f;  // dh^-0.5 * log2(e)

  if (cls < 2) {
#pragma unroll
    for (int i = 0; i < 4; i++) {
      int mbase = tm + wr * 64 + i * 16 + hi * 4;
#pragma unroll
      for (int j = 0; j < 4; j++) {
        int e = tn + wc * 64 + j * 16 + lo;
        int e2 = e & 1023, h = e2 >> 6, d = e2 & 63;
#pragma unroll
        for (int r = 0; r < 4; r++) {
          int mm = mbase + r;
          int b = mm >> 11, n = mm & 2047;
          float v = acc[i][j][r];
          if (cls == 0)
            Qo[(((size_t)(b * NHEAD + h)) * SEQ + n) * DH + d] = f2bf(v * scale);
          else
            Ko[(((size_t)(b * NHEAD + h)) * SEQ + n) * DH + d] = f2bf(v);
        }
      }
    }
  } else {
    // V: bounce through LDS for coalesced transposed writes
#pragma unroll
    for (int i = 0; i < 4; i++) {
#pragma unroll
      for (int j = 0; j < 4; j++) {
        int e = wc * 64 + j * 16 + lo;
#pragma unroll
        for (int r = 0; r < 4; r++) {
          int n = wr * 64 + i * 16 + hi * 4 + r;
          sAll[e * 128 + (((n >> 3) ^ (e & 15)) * 8) + (n & 7)] = (short)f2bf(acc[i][j][r]);
        }
      }
    }
    __syncthreads();
    int er = tid >> 1, half = tid & 1;
    int e2 = tn + er - 2048;
    int h = e2 >> 6, d = e2 & 63;
    int b = tm >> 11, nb = tm & 2047;
    u16* dst = &Vt[(((size_t)(b * NHEAD + h)) * DH + d) * SEQ + nb + half * 64];
#pragma unroll
    for (int k = 0; k < 8; k++) {
      int phys = (half * 8 + k) ^ (er & 15);
      bf16x8 v = *(const bf16x8*)&sAll[er * 128 + phys * 8];
      *(bf16x8*)&dst[k * 8] = v;
    }
  }
}

// ---------------- flash attention (direct-from-L2, reg-pipelined, barrier-free) ----------------
// Q,K: [B*H][N][64] bf16 (Q pre-scaled by dh^-.5*log2e); Vt: [B*H][64][N]; O: [B*N][1024]
// K/V per head = 512 KB -> L2-resident (XCD swizzle keeps a head's blocks on one XCD).
// T14 reg-staging: K(t+1) frags loaded into the alternate reg set at the top of tile t
// (full-tile latency cover); V(t) frags issued before QK^T, consumed after softmax.
// Loop unrolled x2 with named reg sets (no runtime-indexed frag arrays -> no scratch).
__global__ __launch_bounds__(256) void attn_kernel(const u16* __restrict__ Q, const u16* __restrict__ Kd,
                                                   const u16* __restrict__ Vt, u16* __restrict__ O) {
  const int tid = threadIdx.x, wv = tid >> 6, l = tid & 63;
  const int l31 = l & 31, hi5 = l >> 5;

  int lin = blockIdx.y * gridDim.x + blockIdx.x;
  int wgid = (lin & 7) * 64 + (lin >> 3);
  int bx = wgid & 15;
  int bh = wgid >> 4;

  const int qw = bx * 128 + wv * 32;
  const u16* Qb = Q + (size_t)bh * SEQ * DH;
  const u16* Kb = Kd + (size_t)bh * SEQ * DH;
  const u16* Vb = Vt + (size_t)bh * DH * SEQ;

  bf16x8 qf[4];
#pragma unroll
  for (int kd = 0; kd < 4; kd++)
    qf[kd] = *(const bf16x8*)&Qb[(size_t)(qw + l31) * DH + kd * 16 + hi5 * 8];

  f32x16 o0, o1;
#pragma unroll
  for (int r = 0; r < 16; r++) { o0[r] = 0.f; o1[r] = 0.f; }
  float mrun = -1e30f, lsum = 0.f;
  const float THR = 11.0f;

  const u16* Krow0 = &Kb[(size_t)l31 * DH + hi5 * 8];          // + t*64*DH + kd*16
  const u16* Krow1 = &Kb[(size_t)(32 + l31) * DH + hi5 * 8];
  const u16* Vrow0 = &Vb[(size_t)l31 * SEQ + hi5 * 8];         // + t*64 + ks*16
  const u16* Vrow1 = &Vb[(size_t)(32 + l31) * SEQ + hi5 * 8];

  bf16x8 kA0[4], kA1[4], kB0[4], kB1[4];

  auto loadK = [&](bf16x8 (&k0)[4], bf16x8 (&k1)[4], int t) {
    int off = t * 64 * DH;
#pragma unroll
    for (int kd = 0; kd < 4; kd++) {
      k0[kd] = *(const bf16x8*)&Krow0[off + kd * 16];
      k1[kd] = *(const bf16x8*)&Krow1[off + kd * 16];
    }
  };

  auto tile = [&](bf16x8 (&kc0)[4], bf16x8 (&kc1)[4],
                  bf16x8 (&kn0)[4], bf16x8 (&kn1)[4], int t) {
    const int kv0 = t * 64;

    // V(t) frags: issued now, consumed after softmax (~500cy cover)
    bf16x8 vf0[4], vf1[4];
#pragma unroll
    for (int ks = 0; ks < 4; ks++) {
      vf0[ks] = *(const bf16x8*)&Vrow0[kv0 + ks * 16];
      vf1[ks] = *(const bf16x8*)&Vrow1[kv0 + ks * 16];
    }
    // K(t+1) frags into the alternate reg set: full-tile latency cover
    if (t + 1 < SEQ / 64) loadK(kn0, kn1, t + 1);

    // ---- S^T = K Q^T (uses pre-loaded kc) ----
    f32x16 s0, s1;
#pragma unroll
    for (int r = 0; r < 16; r++) { s0[r] = 0.f; s1[r] = 0.f; }
#pragma unroll
    for (int kd = 0; kd < 4; kd++) {
      s0 = __builtin_amdgcn_mfma_f32_32x32x16_bf16(kc0[kd], qf[kd], s0, 0, 0, 0);
      s1 = __builtin_amdgcn_mfma_f32_32x32x16_bf16(kc1[kd], qf[kd], s1, 0, 0, 0);
    }

    // ---- in-register online softmax (log2 domain) ----
    float tr[16];
#pragma unroll
    for (int r = 0; r < 16; r++) tr[r] = fmaxf(s0[r], s1[r]);
#pragma unroll
    for (int st = 8; st > 0; st >>= 1)
#pragma unroll
      for (int r = 0; r < st; r++) tr[r] = fmaxf(tr[r], tr[r + st]);
    float mxa, mxb;
    plswap_f2(tr[0], mxa, mxb);
    float mx = fmaxf(mxa, mxb);

    if (!__all(mx <= mrun + THR)) {
      float mnew = fmaxf(mrun, mx);
      float alpha = __builtin_amdgcn_exp2f(mrun - mnew);
      mrun = mnew;
      lsum *= alpha;
      o0 *= alpha;
      o1 *= alpha;
    }

    float sm[16];
#pragma unroll
    for (int r = 0; r < 16; r++) {
      s0[r] = __builtin_amdgcn_exp2f(s0[r] - mrun);
      s1[r] = __builtin_amdgcn_exp2f(s1[r] - mrun);
      sm[r] = s0[r] + s1[r];
    }
#pragma unroll
    for (int st = 8; st > 0; st >>= 1)
#pragma unroll
      for (int r = 0; r < st; r++) sm[r] += sm[r + st];
    lsum += sm[0];

    // ---- P -> PV B-frags via cvt_pk + permlane32_swap ----
    bf16x8 pa[4];
#pragma unroll
    for (int ks = 0; ks < 4; ks++) {
      const int sft = (ks & 1) * 8;
      float e0 = (ks < 2) ? s0[sft + 0] : s1[sft + 0];
      float e1 = (ks < 2) ? s0[sft + 1] : s1[sft + 1];
      float e2 = (ks < 2) ? s0[sft + 2] : s1[sft + 2];
      float e3 = (ks < 2) ? s0[sft + 3] : s1[sft + 3];
      float e4 = (ks < 2) ? s0[sft + 4] : s1[sft + 4];
      float e5 = (ks < 2) ? s0[sft + 5] : s1[sft + 5];
      float e6 = (ks < 2) ? s0[sft + 6] : s1[sft + 6];
      float e7 = (ks < 2) ? s0[sft + 7] : s1[sft + 7];
      unsigned int w0 = cvtpk(e0, e1);
      unsigned int w1 = cvtpk(e2, e3);
      unsigned int w2 = cvtpk(e4, e5);
      unsigned int w3 = cvtpk(e6, e7);
      plswap_u(w0, w2);
      plswap_u(w1, w3);
      union { unsigned int w[4]; bf16x8 v; } u;
      u.w[0] = w0; u.w[1] = w1; u.w[2] = w2; u.w[3] = w3;
      pa[ks] = u.v;
    }

    // ---- O^T += V^T P^T (vf waits land here, after ~500cy of cover) ----
#pragma unroll
    for (int ks = 0; ks < 4; ks++) {
      o0 = __builtin_amdgcn_mfma_f32_32x32x16_bf16(vf0[ks], pa[ks], o0, 0, 0, 0);
      o1 = __builtin_amdgcn_mfma_f32_32x32x16_bf16(vf1[ks], pa[ks], o1, 0, 0, 0);
    }
  };

  loadK(kA0, kA1, 0);
  for (int t = 0; t < SEQ / 64; t += 2) {
    tile(kA0, kA1, kB0, kB1, t);
    tile(kB0, kB1, kA0, kA1, t + 1);
  }

  float la, lb;
  plswap_f2(lsum, la, lb);
  float inv = 1.0f / (la + lb);

  int b = bh >> 4, h = bh & 15;
  int q = qw + l31;
  size_t orow = ((size_t)(b * SEQ + q)) * INNER + h * 64;
#pragma unroll
  for (int half = 0; half < 2; half++) {
    const f32x16& oo = half ? o1 : o0;
#pragma unroll
    for (int g = 0; g < 4; g++) {
      uint2v pk2;
      pk2[0] = cvtpk(oo[g * 4 + 0] * inv, oo[g * 4 + 1] * inv);
      pk2[1] = cvtpk(oo[g * 4 + 2] * inv, oo[g * 4 + 3] * inv);
      int dv = half * 32 + g * 8 + 4 * hi5;
      *(uint2v*)&O[orow + dv] = pk2;
    }
  }
}

// ---------------- output projection GEMM (BK=32 dbuf prefetch) ----------------
__global__ __launch_bounds__(256) void gemm_out(const u16* __restrict__ A, const u16* __restrict__ W,
                                                const float* __restrict__ bias, float* __restrict__ out) {
  __shared__ short sAll[16384];
  short* sA = sAll;
  short* sB = sAll + 8192;
  const int tid = threadIdx.x;
  const int wv = tid >> 6, l = tid & 63;
  const int lo = l & 15, hi = l >> 4;
  const int wr = wv >> 1, wc = wv & 1;

  int lin = blockIdx.x;
  int wgid = (lin & 7) * 32 + (lin >> 3);
  const int bx = wgid / 32;
  const int by = wgid % 32;
  const int tn = bx * 128, tm = by * 128;

  f32x4 acc[4][4];
#pragma unroll
  for (int i = 0; i < 4; i++)
#pragma unroll
    for (int j = 0; j < 4; j++) acc[i][j] = (f32x4){0.f, 0.f, 0.f, 0.f};

  auto stage = [&](int buf, int kt) {
    int k0 = kt * 32;
    int off = buf * 4096;
#pragma unroll
    for (int c = 0; c < 2; c++) {
      int R0 = wv * 32 + c * 16;
      int r = R0 + (l >> 2);
      int sc = ((l & 3) ^ swz4(r)) * 8;
      async16(&sA[off + R0 * 32], &A[(size_t)(tm + r) * INNER + k0 + sc]);
      async16(&sB[off + R0 * 32], &W[(size_t)(tn + r) * INNER + k0 + sc]);
    }
  };

  stage(0, 0);
  __syncthreads();

  for (int kt = 0; kt < INNER / 32; kt++) {
    const int buf = kt & 1;
    if (kt + 1 < INNER / 32) stage(buf ^ 1, kt + 1);
    bf16x8 af[4], bf[4];
#pragma unroll
    for (int i = 0; i < 4; i++) {
      int r = wr * 64 + i * 16 + lo;
      af[i] = *(const bf16x8*)&sA[buf * 4096 + r * 32 + ((hi ^ swz4(r)) * 8)];
    }
#pragma unroll
    for (int j = 0; j < 4; j++) {
      int r = wc * 64 + j * 16 + lo;
      bf[j] = *(const bf16x8*)&sB[buf * 4096 + r * 32 + ((hi ^ swz4(r)) * 8)];
    }
#pragma unroll
    for (int i = 0; i < 4; i++)
#pragma unroll
      for (int j = 0; j < 4; j++)
        acc[i][j] = __builtin_amdgcn_mfma_f32_16x16x32_bf16(af[i], bf[j], acc[i][j], 0, 0, 0);
    __syncthreads();
  }

#pragma unroll
  for (int i = 0; i < 4; i++) {
    int mbase = tm + wr * 64 + i * 16 + hi * 4;
#pragma unroll
    for (int j = 0; j < 4; j++) {
      int col = tn + wc * 64 + j * 16 + lo;
      float bv = bias[col];
#pragma unroll
      for (int r = 0; r < 4; r++)
        out[(size_t)(mbase + r) * DIMX + col] = acc[i][j][r] + bv;
    }
  }
}

extern "C" void kernel_launch(void* const* d_in, const int* in_sizes, int n_in,
                              void* d_out, int out_size, void* d_ws, size_t ws_size,
                              hipStream_t stream) {
  const float* x     = (const float*)d_in[0];
  const float* w_qkv = (const float*)d_in[1];
  const float* w_out = (const float*)d_in[2];
  const float* b_out = (const float*)d_in[3];

  char* ws = (char*)d_ws;
  u16* xb    = (u16*)(ws);                         // 8 MB
  u16* wqkvb = (u16*)(ws + (size_t)8  * (1<<20));  // 6 MB
  u16* woutb = (u16*)(ws + (size_t)14 * (1<<20));  // 2 MB
  u16* Qd    = (u16*)(ws + (size_t)16 * (1<<20));  // 8 MB
  u16* Kdd   = (u16*)(ws + (size_t)24 * (1<<20));  // 8 MB
  u16* Vtd   = (u16*)(ws + (size_t)32 * (1<<20));  // 8 MB
  u16* Od    = (u16*)(ws + (size_t)40 * (1<<20));  // 8 MB

  cvt_kernel<<<(MTOT * DIMX / 4 + 255) / 256, 256, 0, stream>>>(x, xb, MTOT * DIMX / 4);
  cvt_kernel<<<(EQKV * DIMX / 4 + 255) / 256, 256, 0, stream>>>(w_qkv, wqkvb, EQKV * DIMX / 4);
  cvt_kernel<<<(DIMX * INNER / 4 + 255) / 256, 256, 0, stream>>>(w_out, woutb, DIMX * INNER / 4);

  gemm_qkv<<<768, 256, 0, stream>>>(xb, wqkvb, Qd, Kdd, Vtd);
  attn_kernel<<<dim3(SEQ / 128, BATCH * NHEAD), 256, 0, stream>>>(Qd, Kdd, Vtd, Od);
  gemm_out<<<256, 256, 0, stream>>>(Od, woutb, b_out, (float*)d_out);
}

// Round 9
// 136.655 us; speedup vs baseline: 1.4358x; 1.4267x over previous
//
#include <hip/hip_runtime.h>
#include <hip/hip_bf16.h>
#include <stdint.h>

typedef unsigned short u16;
typedef short bf16x8 __attribute__((ext_vector_type(8)));
typedef float f32x4 __attribute__((ext_vector_type(4)));
typedef float f32x16 __attribute__((ext_vector_type(16)));
typedef u16 u16x4 __attribute__((ext_vector_type(4)));
typedef unsigned int uint2v __attribute__((ext_vector_type(2)));

#define DIMX  1024
#define NHEAD 16
#define DH    64
#define INNER 1024
#define BATCH 2
#define SEQ   2048
#define MTOT  (BATCH*SEQ)   /* 4096 */
#define EQKV  (3*INNER)     /* 3072 */

__device__ __forceinline__ u16 f2bf(float f) {
  unsigned int x = __float_as_uint(f);
  unsigned int r = (x + 0x7FFFu + ((x >> 16) & 1u)) >> 16;
  return (u16)r;
}

__device__ __forceinline__ unsigned int cvtpk(float lo, float hi) {
  unsigned int r;
  asm("v_cvt_pk_bf16_f32 %0, %1, %2" : "=v"(r) : "v"(lo), "v"(hi));
  return r;
}

__device__ __forceinline__ void plswap_u(unsigned int& x, unsigned int& y) {
  auto r = __builtin_amdgcn_permlane32_swap(x, y, false, false);
  x = r[0]; y = r[1];
}
__device__ __forceinline__ void plswap_f2(float v, float& a, float& b) {
  unsigned int x = __float_as_uint(v), y = __float_as_uint(v);
  auto r = __builtin_amdgcn_permlane32_swap(x, y, false, false);
  a = __uint_as_float(r[0]); b = __uint_as_float(r[1]);
}

__device__ __forceinline__ void async16(void* lds, const void* g) {
  __builtin_amdgcn_global_load_lds(
      (const __attribute__((address_space(1))) unsigned int*)g,
      (__attribute__((address_space(3))) unsigned int*)lds,
      16, 0, 0);
}

// staging swizzle: 4 16B-units per 32-col row, unit ^= S(r), S(r)=(r^(r>>2))&3
__device__ __forceinline__ int swz4(int r) { return (r ^ (r >> 2)) & 3; }

// ---------------- fp32 -> bf16 convert ----------------
__global__ void cvt_kernel(const float* __restrict__ in, u16* __restrict__ out, int n4) {
  int i = blockIdx.x * blockDim.x + threadIdx.x;
  if (i < n4) {
    float4 v = ((const float4*)in)[i];
    u16x4 o;
    o[0] = f2bf(v.x); o[1] = f2bf(v.y); o[2] = f2bf(v.z); o[3] = f2bf(v.w);
    ((u16x4*)out)[i] = o;
  }
}

// ---------------- QKV projection GEMM (BK=32 dbuf prefetch) ----------------
__global__ __launch_bounds__(256) void gemm_qkv(const u16* __restrict__ X, const u16* __restrict__ W,
                                                u16* __restrict__ Qo, u16* __restrict__ Ko,
                                                u16* __restrict__ Vt) {
  __shared__ short sAll[16384];
  short* sA = sAll;          // [2][128*32]
  short* sB = sAll + 8192;   // [2][128*32]
  const int tid = threadIdx.x;
  const int wv = tid >> 6, l = tid & 63;
  const int lo = l & 15, hi = l >> 4;
  const int wr = wv >> 1, wc = wv & 1;

  int lin = blockIdx.x;
  int wgid = (lin & 7) * 96 + (lin >> 3);
  const int bx = wgid / 32;
  const int by = wgid % 32;
  const int tn = bx * 128, tm = by * 128;

  f32x4 acc[4][4];
#pragma unroll
  for (int i = 0; i < 4; i++)
#pragma unroll
    for (int j = 0; j < 4; j++) acc[i][j] = (f32x4){0.f, 0.f, 0.f, 0.f};

  auto stage = [&](int buf, int kt) {
    int k0 = kt * 32;
    int off = buf * 4096;
#pragma unroll
    for (int c = 0; c < 2; c++) {
      int R0 = wv * 32 + c * 16;
      int r = R0 + (l >> 2);
      int sc = ((l & 3) ^ swz4(r)) * 8;
      async16(&sA[off + R0 * 32], &X[(size_t)(tm + r) * DIMX + k0 + sc]);
      async16(&sB[off + R0 * 32], &W[(size_t)(tn + r) * DIMX + k0 + sc]);
    }
  };

  stage(0, 0);
  __syncthreads();

  for (int kt = 0; kt < DIMX / 32; kt++) {
    const int buf = kt & 1;
    if (kt + 1 < DIMX / 32) stage(buf ^ 1, kt + 1);
    bf16x8 af[4], bf[4];
#pragma unroll
    for (int i = 0; i < 4; i++) {
      int r = wr * 64 + i * 16 + lo;
      af[i] = *(const bf16x8*)&sA[buf * 4096 + r * 32 + ((hi ^ swz4(r)) * 8)];
    }
#pragma unroll
    for (int j = 0; j < 4; j++) {
      int r = wc * 64 + j * 16 + lo;
      bf[j] = *(const bf16x8*)&sB[buf * 4096 + r * 32 + ((hi ^ swz4(r)) * 8)];
    }
#pragma unroll
    for (int i = 0; i < 4; i++)
#pragma unroll
      for (int j = 0; j < 4; j++)
        acc[i][j] = __builtin_amdgcn_mfma_f32_16x16x32_bf16(af[i], bf[j], acc[i][j], 0, 0, 0);
    __syncthreads();
  }

  const int cls = tn >> 10;
  const float scale = 0.125f * 1.44269504088896f;  // dh^-0.5 * log2(e)

  if (cls < 2) {
#pragma unroll
    for (int i = 0; i < 4; i++) {
      int mbase = tm + wr * 64 + i * 16 + hi * 4;
#pragma unroll
      for (int j = 0; j < 4; j++) {
        int e = tn + wc * 64 + j * 16 + lo;
        int e2 = e & 1023, h = e2 >> 6, d = e2 & 63;
#pragma unroll
        for (int r = 0; r < 4; r++) {
          int mm = mbase + r;
          int b = mm >> 11, n = mm & 2047;
          float v = acc[i][j][r];
          if (cls == 0)
            Qo[(((size_t)(b * NHEAD + h)) * SEQ + n) * DH + d] = f2bf(v * scale);
          else
            Ko[(((size_t)(b * NHEAD + h)) * SEQ + n) * DH + d] = f2bf(v);
        }
      }
    }
  } else {
    // V: bounce through LDS for coalesced transposed writes
#pragma unroll
    for (int i = 0; i < 4; i++) {
#pragma unroll
      for (int j = 0; j < 4; j++) {
        int e = wc * 64 + j * 16 + lo;
#pragma unroll
        for (int r = 0; r < 4; r++) {
          int n = wr * 64 + i * 16 + hi * 4 + r;
          sAll[e * 128 + (((n >> 3) ^ (e & 15)) * 8) + (n & 7)] = (short)f2bf(acc[i][j][r]);
        }
      }
    }
    __syncthreads();
    int er = tid >> 1, half = tid & 1;
    int e2 = tn + er - 2048;
    int h = e2 >> 6, d = e2 & 63;
    int b = tm >> 11, nb = tm & 2047;
    u16* dst = &Vt[(((size_t)(b * NHEAD + h)) * DH + d) * SEQ + nb + half * 64];
#pragma unroll
    for (int k = 0; k < 8; k++) {
      int phys = (half * 8 + k) ^ (er & 15);
      bf16x8 v = *(const bf16x8*)&sAll[er * 128 + phys * 8];
      *(bf16x8*)&dst[k * 8] = v;
    }
  }
}

// ---------------- flash attention (LDS dbuf + upfront frag reads + setprio) ----------------
// Q,K: [B*H][N][64] bf16 (Q pre-scaled by dh^-.5*log2e); Vt: [B*H][64][N]; O: [B*N][1024]
// Round-6 structure (coalesced global_load_lds staging, 1 barrier/tile) with the
// ds_read->MFMA chain fixed: ALL 16 ds_read_b128 issued up front as independent ops
// (one latency exposure instead of 16), MFMA clusters wrapped in setprio (T5).
__global__ __launch_bounds__(256) void attn_kernel(const u16* __restrict__ Q, const u16* __restrict__ Kd,
                                                   const u16* __restrict__ Vt, u16* __restrict__ O) {
  __shared__ short sK[2][64 * 64];
  __shared__ short sV[2][64 * 64];
  const int tid = threadIdx.x, wv = tid >> 6, l = tid & 63;
  const int l31 = l & 31, hi5 = l >> 5, l7 = l & 7;

  int lin = blockIdx.y * gridDim.x + blockIdx.x;
  int wgid = (lin & 7) * 64 + (lin >> 3);
  int bx = wgid & 15;
  int bh = wgid >> 4;

  const int qw = bx * 128 + wv * 32;
  const u16* Qb = Q + (size_t)bh * SEQ * DH;
  const u16* Kb = Kd + (size_t)bh * SEQ * DH;
  const u16* Vb = Vt + (size_t)bh * DH * SEQ;

  bf16x8 qf[4];
#pragma unroll
  for (int kd = 0; kd < 4; kd++)
    qf[kd] = *(const bf16x8*)&Qb[(size_t)(qw + l31) * DH + kd * 16 + hi5 * 8];

  f32x16 o0, o1;
#pragma unroll
  for (int r = 0; r < 16; r++) { o0[r] = 0.f; o1[r] = 0.f; }
  float mrun = -1e30f, lsum = 0.f;
  const float THR = 11.0f;

  auto stage = [&](int buf, int t) {
    int kv0 = t * 64;
#pragma unroll
    for (int c = 0; c < 2; c++) {
      int rbase = wv * 16 + c * 8;
      int gr = rbase + (l >> 3);
      int sc = ((l & 7) ^ (l >> 3)) * 8;
      async16(&sK[buf][rbase * 64], &Kb[(size_t)(kv0 + gr) * DH + sc]);
      async16(&sV[buf][rbase * 64], &Vb[(size_t)gr * SEQ + kv0 + sc]);
    }
  };

  stage(0, 0);
  __syncthreads();

  for (int t = 0; t < SEQ / 64; t++) {
    const int cur = t & 1;
    if (t + 1 < SEQ / 64) stage(cur ^ 1, t + 1);   // global->LDS prefetch overlaps all compute

    // ---- ALL frag reads up front: 16 independent ds_read_b128 ----
    bf16x8 kf0[4], kf1[4], vf0[4], vf1[4];
#pragma unroll
    for (int kd = 0; kd < 4; kd++) {
      int c16 = ((kd * 2 + hi5) ^ l7) * 8;
      kf0[kd] = *(const bf16x8*)&sK[cur][l31 * 64 + c16];
      kf1[kd] = *(const bf16x8*)&sK[cur][(32 + l31) * 64 + c16];
      vf0[kd] = *(const bf16x8*)&sV[cur][l31 * 64 + c16];
      vf1[kd] = *(const bf16x8*)&sV[cur][(32 + l31) * 64 + c16];
    }

    // ---- S^T = K Q^T ----
    f32x16 s0, s1;
#pragma unroll
    for (int r = 0; r < 16; r++) { s0[r] = 0.f; s1[r] = 0.f; }
    __builtin_amdgcn_s_setprio(1);
#pragma unroll
    for (int kd = 0; kd < 4; kd++) {
      s0 = __builtin_amdgcn_mfma_f32_32x32x16_bf16(kf0[kd], qf[kd], s0, 0, 0, 0);
      s1 = __builtin_amdgcn_mfma_f32_32x32x16_bf16(kf1[kd], qf[kd], s1, 0, 0, 0);
    }
    __builtin_amdgcn_s_setprio(0);

    // ---- in-register online softmax (log2 domain) ----
    float tr[16];
#pragma unroll
    for (int r = 0; r < 16; r++) tr[r] = fmaxf(s0[r], s1[r]);
#pragma unroll
    for (int st = 8; st > 0; st >>= 1)
#pragma unroll
      for (int r = 0; r < st; r++) tr[r] = fmaxf(tr[r], tr[r + st]);
    float mxa, mxb;
    plswap_f2(tr[0], mxa, mxb);
    float mx = fmaxf(mxa, mxb);

    if (!__all(mx <= mrun + THR)) {
      float mnew = fmaxf(mrun, mx);
      float alpha = __builtin_amdgcn_exp2f(mrun - mnew);
      mrun = mnew;
      lsum *= alpha;
      o0 *= alpha;
      o1 *= alpha;
    }

    float sm[16];
#pragma unroll
    for (int r = 0; r < 16; r++) {
      s0[r] = __builtin_amdgcn_exp2f(s0[r] - mrun);
      s1[r] = __builtin_amdgcn_exp2f(s1[r] - mrun);
      sm[r] = s0[r] + s1[r];
    }
#pragma unroll
    for (int st = 8; st > 0; st >>= 1)
#pragma unroll
      for (int r = 0; r < st; r++) sm[r] += sm[r + st];
    lsum += sm[0];

    // ---- P -> PV B-frags via cvt_pk + permlane32_swap ----
    bf16x8 pa[4];
#pragma unroll
    for (int ks = 0; ks < 4; ks++) {
      const int sft = (ks & 1) * 8;
      float e0 = (ks < 2) ? s0[sft + 0] : s1[sft + 0];
      float e1 = (ks < 2) ? s0[sft + 1] : s1[sft + 1];
      float e2 = (ks < 2) ? s0[sft + 2] : s1[sft + 2];
      float e3 = (ks < 2) ? s0[sft + 3] : s1[sft + 3];
      float e4 = (ks < 2) ? s0[sft + 4] : s1[sft + 4];
      float e5 = (ks < 2) ? s0[sft + 5] : s1[sft + 5];
      float e6 = (ks < 2) ? s0[sft + 6] : s1[sft + 6];
      float e7 = (ks < 2) ? s0[sft + 7] : s1[sft + 7];
      unsigned int w0 = cvtpk(e0, e1);
      unsigned int w1 = cvtpk(e2, e3);
      unsigned int w2 = cvtpk(e4, e5);
      unsigned int w3 = cvtpk(e6, e7);
      plswap_u(w0, w2);
      plswap_u(w1, w3);
      union { unsigned int w[4]; bf16x8 v; } u;
      u.w[0] = w0; u.w[1] = w1; u.w[2] = w2; u.w[3] = w3;
      pa[ks] = u.v;
    }

    // ---- O^T += V^T P^T ----
    __builtin_amdgcn_s_setprio(1);
#pragma unroll
    for (int ks = 0; ks < 4; ks++) {
      o0 = __builtin_amdgcn_mfma_f32_32x32x16_bf16(vf0[ks], pa[ks], o0, 0, 0, 0);
      o1 = __builtin_amdgcn_mfma_f32_32x32x16_bf16(vf1[ks], pa[ks], o1, 0, 0, 0);
    }
    __builtin_amdgcn_s_setprio(0);
    __syncthreads();
  }

  float la, lb;
  plswap_f2(lsum, la, lb);
  float inv = 1.0f / (la + lb);

  int b = bh >> 4, h = bh & 15;
  int q = qw + l31;
  size_t orow = ((size_t)(b * SEQ + q)) * INNER + h * 64;
#pragma unroll
  for (int half = 0; half < 2; half++) {
    const f32x16& oo = half ? o1 : o0;
#pragma unroll
    for (int g = 0; g < 4; g++) {
      uint2v pk2;
      pk2[0] = cvtpk(oo[g * 4 + 0] * inv, oo[g * 4 + 1] * inv);
      pk2[1] = cvtpk(oo[g * 4 + 2] * inv, oo[g * 4 + 3] * inv);
      int dv = half * 32 + g * 8 + 4 * hi5;
      *(uint2v*)&O[orow + dv] = pk2;
    }
  }
}

// ---------------- output projection GEMM (BK=32 dbuf prefetch) ----------------
__global__ __launch_bounds__(256) void gemm_out(const u16* __restrict__ A, const u16* __restrict__ W,
                                                const float* __restrict__ bias, float* __restrict__ out) {
  __shared__ short sAll[16384];
  short* sA = sAll;
  short* sB = sAll + 8192;
  const int tid = threadIdx.x;
  const int wv = tid >> 6, l = tid & 63;
  const int lo = l & 15, hi = l >> 4;
  const int wr = wv >> 1, wc = wv & 1;

  int lin = blockIdx.x;
  int wgid = (lin & 7) * 32 + (lin >> 3);
  const int bx = wgid / 32;
  const int by = wgid % 32;
  const int tn = bx * 128, tm = by * 128;

  f32x4 acc[4][4];
#pragma unroll
  for (int i = 0; i < 4; i++)
#pragma unroll
    for (int j = 0; j < 4; j++) acc[i][j] = (f32x4){0.f, 0.f, 0.f, 0.f};

  auto stage = [&](int buf, int kt) {
    int k0 = kt * 32;
    int off = buf * 4096;
#pragma unroll
    for (int c = 0; c < 2; c++) {
      int R0 = wv * 32 + c * 16;
      int r = R0 + (l >> 2);
      int sc = ((l & 3) ^ swz4(r)) * 8;
      async16(&sA[off + R0 * 32], &A[(size_t)(tm + r) * INNER + k0 + sc]);
      async16(&sB[off + R0 * 32], &W[(size_t)(tn + r) * INNER + k0 + sc]);
    }
  };

  stage(0, 0);
  __syncthreads();

  for (int kt = 0; kt < INNER / 32; kt++) {
    const int buf = kt & 1;
    if (kt + 1 < INNER / 32) stage(buf ^ 1, kt + 1);
    bf16x8 af[4], bf[4];
#pragma unroll
    for (int i = 0; i < 4; i++) {
      int r = wr * 64 + i * 16 + lo;
      af[i] = *(const bf16x8*)&sA[buf * 4096 + r * 32 + ((hi ^ swz4(r)) * 8)];
    }
#pragma unroll
    for (int j = 0; j < 4; j++) {
      int r = wc * 64 + j * 16 + lo;
      bf[j] = *(const bf16x8*)&sB[buf * 4096 + r * 32 + ((hi ^ swz4(r)) * 8)];
    }
#pragma unroll
    for (int i = 0; i < 4; i++)
#pragma unroll
      for (int j = 0; j < 4; j++)
        acc[i][j] = __builtin_amdgcn_mfma_f32_16x16x32_bf16(af[i], bf[j], acc[i][j], 0, 0, 0);
    __syncthreads();
  }

#pragma unroll
  for (int i = 0; i < 4; i++) {
    int mbase = tm + wr * 64 + i * 16 + hi * 4;
#pragma unroll
    for (int j = 0; j < 4; j++) {
      int col = tn + wc * 64 + j * 16 + lo;
      float bv = bias[col];
#pragma unroll
      for (int r = 0; r < 4; r++)
        out[(size_t)(mbase + r) * DIMX + col] = acc[i][j][r] + bv;
    }
  }
}

extern "C" void kernel_launch(void* const* d_in, const int* in_sizes, int n_in,
                              void* d_out, int out_size, void* d_ws, size_t ws_size,
                              hipStream_t stream) {
  const float* x     = (const float*)d_in[0];
  const float* w_qkv = (const float*)d_in[1];
  const float* w_out = (const float*)d_in[2];
  const float* b_out = (const float*)d_in[3];

  char* ws = (char*)d_ws;
  u16* xb    = (u16*)(ws);                         // 8 MB
  u16* wqkvb = (u16*)(ws + (size_t)8  * (1<<20));  // 6 MB
  u16* woutb = (u16*)(ws + (size_t)14 * (1<<20));  // 2 MB
  u16* Qd    = (u16*)(ws + (size_t)16 * (1<<20));  // 8 MB
  u16* Kdd   = (u16*)(ws + (size_t)24 * (1<<20));  // 8 MB
  u16* Vtd   = (u16*)(ws + (size_t)32 * (1<<20));  // 8 MB
  u16* Od    = (u16*)(ws + (size_t)40 * (1<<20));  // 8 MB

  cvt_kernel<<<(MTOT * DIMX / 4 + 255) / 256, 256, 0, stream>>>(x, xb, MTOT * DIMX / 4);
  cvt_kernel<<<(EQKV * DIMX / 4 + 255) / 256, 256, 0, stream>>>(w_qkv, wqkvb, EQKV * DIMX / 4);
  cvt_kernel<<<(DIMX * INNER / 4 + 255) / 256, 256, 0, stream>>>(w_out, woutb, DIMX * INNER / 4);

  gemm_qkv<<<768, 256, 0, stream>>>(xb, wqkvb, Qd, Kdd, Vtd);
  attn_kernel<<<dim3(SEQ / 128, BATCH * NHEAD), 256, 0, stream>>>(Qd, Kdd, Vtd, Od);
  gemm_out<<<256, 256, 0, stream>>>(Od, woutb, b_out, (float*)d_out);
}